// Round 1
// baseline (991.282 us; speedup 1.0000x reference)
//
#include <hip/hip_runtime.h>
#include <math.h>

// Problem constants
#define B_  4
#define L_  8192
#define D_  512
#define LR  (L_ - 1)          // cos rows per batch: l = 0..8190

// GEMM tiling
#define BM  64
#define BN  64
#define BK  32
#define NCT (D_ / BN)         // 8 col tiles
#define NRT ((LR + BM - 1) / BM)  // 128 row tiles per batch

// Scan chunking
#define CHUNK 128
#define NCHUNK (L_ / CHUNK)   // 64 chunks per batch

// ---------------------------------------------------------------------------
// Kernel 1: fused Q/K' GEMM with per-(row, colblock) partial reductions.
// Q[l]  = h[l]   @ Wq^T   (row l of batch)
// K'[l] = h[l+1] @ Wk^T   (shifted so dot is row-aligned)
// Emits partials: nq = sum_j Q^2, nk = sum_j K'^2, dot = sum_j Q*K'
// part layout: [NCT][B][L][3]  (row index l < LR used)
// ---------------------------------------------------------------------------
__global__ __launch_bounds__(256) void qk_gemm(
    const float* __restrict__ h,
    const float* __restrict__ wq,
    const float* __restrict__ wk,
    float* __restrict__ part)
{
    const int ct = blockIdx.x;   // 0..NCT-1
    const int rt = blockIdx.y;   // 0..NRT-1
    const int b  = blockIdx.z;   // 0..B_-1
    const int t  = threadIdx.x;  // 0..255

    __shared__ float a_lds[BK][BM + 2];   // rows r0..r0+64 (65 used)
    __shared__ float bq_lds[BK][BN + 2];
    __shared__ float bk_lds[BK][BN + 2];

    const float* hb = h + (size_t)b * (size_t)L_ * D_;
    const int r0 = rt * BM;

    const int ty = t >> 4;       // 0..15 row group
    const int tx = t & 15;       // 0..15 col group
    const int m0 = ty * 4;
    const int c0 = tx * 4;

    float accq[4][4];
    float acck[4][4];
#pragma unroll
    for (int r = 0; r < 4; ++r)
#pragma unroll
        for (int c = 0; c < 4; ++c) { accq[r][c] = 0.f; acck[r][c] = 0.f; }

    for (int k0 = 0; k0 < D_; k0 += BK) {
        // stage A: 65 rows x BK cols
        for (int i = t; i < (BM + 1) * BK; i += 256) {
            int ra = i / BK;
            int kk = i % BK;
            int l = r0 + ra;
            if (l > L_ - 1) l = L_ - 1;   // clamp (value unused for invalid rows)
            a_lds[kk][ra] = hb[(size_t)l * D_ + k0 + kk];
        }
        // stage B: Wq/Wk col tile, BN x BK
        for (int i = t; i < BN * BK; i += 256) {
            int j  = i / BK;
            int kk = i % BK;
            int col = ct * BN + j;
            bq_lds[kk][j] = wq[(size_t)col * D_ + k0 + kk];
            bk_lds[kk][j] = wk[(size_t)col * D_ + k0 + kk];
        }
        __syncthreads();

#pragma unroll
        for (int kk = 0; kk < BK; ++kk) {
            float a[5];
#pragma unroll
            for (int r = 0; r < 5; ++r) a[r] = a_lds[kk][m0 + r];
            float bq[4], bk[4];
#pragma unroll
            for (int c = 0; c < 4; ++c) {
                bq[c] = bq_lds[kk][c0 + c];
                bk[c] = bk_lds[kk][c0 + c];
            }
#pragma unroll
            for (int r = 0; r < 4; ++r)
#pragma unroll
                for (int c = 0; c < 4; ++c) {
                    accq[r][c] += a[r]     * bq[c];
                    acck[r][c] += a[r + 1] * bk[c];
                }
        }
        __syncthreads();
    }

    // per-row partial reductions over this block's 64 columns
#pragma unroll
    for (int r = 0; r < 4; ++r) {
        float pq = 0.f, pk = 0.f, pd = 0.f;
#pragma unroll
        for (int c = 0; c < 4; ++c) {
            pq += accq[r][c] * accq[r][c];
            pk += acck[r][c] * acck[r][c];
            pd += accq[r][c] * acck[r][c];
        }
        // reduce across the 16 lanes (tx) sharing this row strip
#pragma unroll
        for (int off = 1; off < 16; off <<= 1) {
            pq += __shfl_xor(pq, off);
            pk += __shfl_xor(pk, off);
            pd += __shfl_xor(pd, off);
        }
        if (tx == 0) {
            int l = r0 + m0 + r;
            if (l < LR) {
                size_t o = ((((size_t)ct * B_) + b) * L_ + l) * 3;
                part[o + 0] = pq;
                part[o + 1] = pk;
                part[o + 2] = pd;
            }
        }
    }
}

// ---------------------------------------------------------------------------
// Kernel 2: reduce partials -> p[b][t]  (p[b][0] = 1)
// ---------------------------------------------------------------------------
__global__ __launch_bounds__(256) void cos_reduce(
    const float* __restrict__ part, float* __restrict__ p)
{
    int idx = blockIdx.x * 256 + threadIdx.x;
    if (idx >= B_ * L_) return;
    int b = idx / L_;
    int t = idx % L_;
    if (t == 0) { p[idx] = 1.0f; return; }
    int l = t - 1;   // cos row, 0..8190
    float nq = 0.f, nk = 0.f, dt = 0.f;
#pragma unroll
    for (int ct = 0; ct < NCT; ++ct) {
        size_t o = ((((size_t)ct * B_) + b) * L_ + l) * 3;
        nq += part[o + 0];
        nk += part[o + 1];
        dt += part[o + 2];
    }
    float qn = sqrtf(nq); if (qn < 1e-12f) qn = 1e-12f;
    float kn = sqrtf(nk); if (kn < 1e-12f) kn = 1e-12f;
    float cs = dt / (qn * kn);
    float pr = 0.5f * (1.0f - cs);
    pr = fminf(fmaxf(pr, 0.0f), 1.0f);
    p[idx] = pr;
}

// ---------------------------------------------------------------------------
// Kernel 3: per-chunk scan aggregates.
// For chunk c of batch b: A_c = prod over boundary steps of (1-p),
// B_c[d] = chunk-local EMA state starting from 0.
// ---------------------------------------------------------------------------
__global__ __launch_bounds__(512) void scan_a(
    const float* __restrict__ h, const float* __restrict__ p,
    float* __restrict__ Bc, float* __restrict__ Ac)
{
    const int d = threadIdx.x;       // 0..511
    const int c = blockIdx.x;        // chunk
    const int b = blockIdx.y;
    const int l0 = c * CHUNK;

    const float* hb = h + ((size_t)b * L_ + l0) * D_ + d;
    const float* pb = p + (size_t)b * L_ + l0;

    float st = 0.f;
    float ap = 1.f;
    for (int i = 0; i < CHUNK; ++i) {
        float pr = pb[i];
        if (pr > 0.5f) {
            float a = 1.f - pr;
            st = a * st + pr * hb[(size_t)i * D_];
            ap *= a;
        }
    }
    Bc[((size_t)b * NCHUNK + c) * D_ + d] = st;
    if (d == 0) Ac[b * NCHUNK + c] = ap;
}

// ---------------------------------------------------------------------------
// Kernel 4: scan chunk aggregates across chunks (per batch), emit carry-in
// state for every chunk. carry[b][c][d] = state BEFORE chunk c.
// ---------------------------------------------------------------------------
__global__ __launch_bounds__(512) void scan_b(
    const float* __restrict__ Ac, const float* __restrict__ Bc,
    const float* __restrict__ det, float* __restrict__ carry)
{
    const int d = threadIdx.x;
    const int b = blockIdx.x;
    float st = det[(size_t)b * D_ + d];
    for (int c = 0; c < NCHUNK; ++c) {
        carry[((size_t)b * NCHUNK + c) * D_ + d] = st;
        st = Ac[b * NCHUNK + c] * st + Bc[((size_t)b * NCHUNK + c) * D_ + d];
    }
}

// ---------------------------------------------------------------------------
// Kernel 5: apply — replay chunk recurrence from carry-in, write output.
// ---------------------------------------------------------------------------
__global__ __launch_bounds__(512) void scan_c(
    const float* __restrict__ h, const float* __restrict__ p,
    const float* __restrict__ res, const float* __restrict__ carry,
    float* __restrict__ out)
{
    const int d = threadIdx.x;
    const int c = blockIdx.x;
    const int b = blockIdx.y;
    const int l0 = c * CHUNK;

    size_t base = ((size_t)b * L_ + l0) * D_ + d;
    const float* pb = p + (size_t)b * L_ + l0;

    float st = carry[((size_t)b * NCHUNK + c) * D_ + d];
    for (int i = 0; i < CHUNK; ++i) {
        float pr = pb[i];
        if (pr > 0.5f) {
            st = (1.f - pr) * st + pr * h[base + (size_t)i * D_];
        }
        out[base + (size_t)i * D_] = res[base + (size_t)i * D_] + st;
    }
}

// ---------------------------------------------------------------------------
extern "C" void kernel_launch(void* const* d_in, const int* in_sizes, int n_in,
                              void* d_out, int out_size, void* d_ws, size_t ws_size,
                              hipStream_t stream)
{
    const float* h   = (const float*)d_in[0];   // (B,L,D)
    const float* res = (const float*)d_in[1];   // (B,L,D)
    const float* wq  = (const float*)d_in[2];   // (D,D)
    const float* wk  = (const float*)d_in[3];   // (D,D)
    const float* det = (const float*)d_in[4];   // (B,D)
    float* out = (float*)d_out;

    // workspace layout (floats)
    float* ws = (float*)d_ws;
    float* part  = ws;                                    // NCT*B*L*3
    float* p     = part + (size_t)NCT * B_ * L_ * 3;      // B*L
    float* Ac    = p    + (size_t)B_ * L_;                // B*NCHUNK
    float* Bc    = Ac   + (size_t)B_ * NCHUNK;            // B*NCHUNK*D
    float* carry = Bc   + (size_t)B_ * NCHUNK * D_;       // B*NCHUNK*D

    qk_gemm<<<dim3(NCT, NRT, B_), 256, 0, stream>>>(h, wq, wk, part);
    cos_reduce<<<(B_ * L_ + 255) / 256, 256, 0, stream>>>(part, p);
    scan_a<<<dim3(NCHUNK, B_), 512, 0, stream>>>(h, p, Bc, Ac);
    scan_b<<<B_, 512, 0, stream>>>(Ac, Bc, det, carry);
    scan_c<<<dim3(NCHUNK, B_), 512, 0, stream>>>(h, p, res, carry, out);
}

// Round 2
// 296.104 us; speedup vs baseline: 3.3477x; 3.3477x over previous
//
#include <hip/hip_runtime.h>
#include <math.h>

// Problem constants
#define B_  4
#define L_  8192
#define D_  512
#define LR  (L_ - 1)

// MFMA GEMM tiling
#define BM   128              // rows per block
#define BKK  32               // k per step
#define NSTEP (D_ / BKK)      // 16
#define NCT  4                // col tiles of 128
#define NRT  (L_ / BM)        // 64 row tiles

// Scan chunking
#define CHUNK 128
#define NCHUNK (L_ / CHUNK)

#define MAXFIX 16380
#define FIX_TAU 1.5e-4f

typedef short bf16x8 __attribute__((ext_vector_type(8)));
typedef float f32x4 __attribute__((ext_vector_type(4)));
typedef unsigned short u16;
typedef u16 ushort8 __attribute__((ext_vector_type(8)));

__device__ __forceinline__ u16 f2bf_rne(float f) {
    unsigned u = __float_as_uint(f);
    unsigned r = (u + 0x7FFFu + ((u >> 16) & 1u)) >> 16;
    return (u16)r;
}
__device__ __forceinline__ float bf2f(u16 h) {
    return __uint_as_float(((unsigned)h) << 16);
}

// ---------------------------------------------------------------------------
// Weight conversion: fp32 -> (hi, lo) bf16 pairs
// ---------------------------------------------------------------------------
__global__ __launch_bounds__(256) void conv_w(
    const float* __restrict__ wq, const float* __restrict__ wk,
    u16* __restrict__ qh, u16* __restrict__ ql,
    u16* __restrict__ kh, u16* __restrict__ kl)
{
    int i = blockIdx.x * 256 + threadIdx.x;
    if (i >= D_ * D_) return;
    float a = wq[i];
    u16 h = f2bf_rne(a);
    qh[i] = h; ql[i] = f2bf_rne(a - bf2f(h));
    float c = wk[i];
    u16 h2 = f2bf_rne(c);
    kh[i] = h2; kl[i] = f2bf_rne(c - bf2f(h2));
}

__global__ void zero_fix(int* c) { if (threadIdx.x == 0 && blockIdx.x == 0) *c = 0; }

// ---------------------------------------------------------------------------
// Split-bf16 MFMA kernel: per block computes 128 rows x 128 cols of both
// Q = h @ Wq^T and Kshift = h(+1) @ Wk^T, then per-row partials over cols.
// part layout: [NCT][B][L][3]
// ---------------------------------------------------------------------------
__global__ __launch_bounds__(256, 2) void qk_mfma(
    const float* __restrict__ h,
    const u16* __restrict__ wqh, const u16* __restrict__ wql,
    const u16* __restrict__ wkh, const u16* __restrict__ wkl,
    float* __restrict__ part)
{
    const int ct = blockIdx.x;
    const int rt = blockIdx.y;
    const int b  = blockIdx.z;
    const int t  = threadIdx.x;
    const int wid = t >> 6, lane = t & 63;
    const int l15 = lane & 15, l4 = lane >> 4;

    __shared__ u16 ah[129 * 32];
    __shared__ u16 al[129 * 32];
    __shared__ float red[4][BM][3];

    const int r0 = rt * BM;
    const size_t hbase = (size_t)b * L_ * D_;

    // staging assignments: 129 rows x 4 kb-groups = 516 chunks of 8 floats
    int srow[3], skb[3]; const float* sptr[3]; bool svalid[3];
#pragma unroll
    for (int j = 0; j < 3; ++j) {
        int i = t + j * 256;
        svalid[j] = (i < 516);
        int row = svalid[j] ? (i >> 2) : 0;
        int kb  = svalid[j] ? (i & 3) : 0;
        srow[j] = row; skb[j] = kb;
        int gr = r0 + row; if (gr > L_ - 1) gr = L_ - 1;
        sptr[j] = h + hbase + (size_t)gr * D_ + kb * 8;
    }

    // B-fragment global offsets (advance by BKK per step)
    const int colb = ct * 128 + wid * 32;
    size_t boff[2];
    boff[0] = (size_t)(colb + 0 * 16 + l15) * D_ + l4 * 8;
    boff[1] = (size_t)(colb + 1 * 16 + l15) * D_ + l4 * 8;

    // LDS read offsets (constant across k-steps); XOR swizzle kb^=(row&3)
    int aq_off[8], ak_off[8];
#pragma unroll
    for (int rf = 0; rf < 8; ++rf) {
        int rq = rf * 16 + l15;
        aq_off[rf] = rq * 32 + ((l4 ^ (rq & 3)) * 8);
        int rk = rq + 1;
        ak_off[rf] = rk * 32 + ((l4 ^ (rk & 3)) * 8);
    }

    f32x4 accq[8][2], acck[8][2];
    const f32x4 zero = {0.f, 0.f, 0.f, 0.f};
#pragma unroll
    for (int rf = 0; rf < 8; ++rf)
#pragma unroll
        for (int cf = 0; cf < 2; ++cf) { accq[rf][cf] = zero; acck[rf][cf] = zero; }

    for (int s = 0; s < NSTEP; ++s) {
        __syncthreads();
        // stage A rows r0..r0+128 (fp32 -> hi/lo bf16) into LDS
#pragma unroll
        for (int j = 0; j < 3; ++j) if (svalid[j]) {
            const float4* p4 = (const float4*)(sptr[j]);
            float4 v0 = p4[0], v1 = p4[1];
            float f[8] = {v0.x, v0.y, v0.z, v0.w, v1.x, v1.y, v1.z, v1.w};
            ushort8 hv, lv;
#pragma unroll
            for (int e = 0; e < 8; ++e) {
                u16 hh = f2bf_rne(f[e]);
                hv[e] = (u16)hh;
                lv[e] = f2bf_rne(f[e] - bf2f(hh));
            }
            int off = srow[j] * 32 + ((skb[j] ^ (srow[j] & 3)) * 8);
            *(ushort8*)(&ah[off]) = hv;
            *(ushort8*)(&al[off]) = lv;
            sptr[j] += BKK;
        }
        // B fragments straight from global (L2-resident weights)
        bf16x8 bqh[2], bql[2], bkh[2], bkl[2];
#pragma unroll
        for (int cf = 0; cf < 2; ++cf) {
            size_t o = boff[cf] + (size_t)s * BKK;
            bqh[cf] = *(const bf16x8*)(wqh + o);
            bql[cf] = *(const bf16x8*)(wql + o);
            bkh[cf] = *(const bf16x8*)(wkh + o);
            bkl[cf] = *(const bf16x8*)(wkl + o);
        }
        __syncthreads();
#pragma unroll
        for (int rf = 0; rf < 8; ++rf) {
            bf16x8 aqh = *(const bf16x8*)(&ah[aq_off[rf]]);
            bf16x8 aql = *(const bf16x8*)(&al[aq_off[rf]]);
            bf16x8 akh = *(const bf16x8*)(&ah[ak_off[rf]]);
            bf16x8 akl = *(const bf16x8*)(&al[ak_off[rf]]);
#pragma unroll
            for (int cf = 0; cf < 2; ++cf) {
                f32x4 a0 = accq[rf][cf];
                a0 = __builtin_amdgcn_mfma_f32_16x16x32_bf16(aqh, bqh[cf], a0, 0, 0, 0);
                a0 = __builtin_amdgcn_mfma_f32_16x16x32_bf16(aqh, bql[cf], a0, 0, 0, 0);
                a0 = __builtin_amdgcn_mfma_f32_16x16x32_bf16(aql, bqh[cf], a0, 0, 0, 0);
                accq[rf][cf] = a0;
                f32x4 a1 = acck[rf][cf];
                a1 = __builtin_amdgcn_mfma_f32_16x16x32_bf16(akh, bkh[cf], a1, 0, 0, 0);
                a1 = __builtin_amdgcn_mfma_f32_16x16x32_bf16(akh, bkl[cf], a1, 0, 0, 0);
                a1 = __builtin_amdgcn_mfma_f32_16x16x32_bf16(akl, bkh[cf], a1, 0, 0, 0);
                acck[rf][cf] = a1;
            }
        }
    }
    __syncthreads();

    // per-row partials over this block's 128 cols
    // C/D layout: col = lane&15, row = (lane>>4)*4 + reg  [verified m89]
#pragma unroll
    for (int rf = 0; rf < 8; ++rf) {
#pragma unroll
        for (int reg = 0; reg < 4; ++reg) {
            float q0 = accq[rf][0][reg], q1 = accq[rf][1][reg];
            float k0v = acck[rf][0][reg], k1v = acck[rf][1][reg];
            float pq = q0 * q0 + q1 * q1;
            float pk = k0v * k0v + k1v * k1v;
            float pd = q0 * k0v + q1 * k1v;
#pragma unroll
            for (int off = 1; off < 16; off <<= 1) {
                pq += __shfl_xor(pq, off);
                pk += __shfl_xor(pk, off);
                pd += __shfl_xor(pd, off);
            }
            if (l15 == 0) {
                int row = rf * 16 + l4 * 4 + reg;
                red[wid][row][0] = pq;
                red[wid][row][1] = pk;
                red[wid][row][2] = pd;
            }
        }
    }
    __syncthreads();
    if (t < BM) {
        int row = t;
        float pq = red[0][row][0] + red[1][row][0] + red[2][row][0] + red[3][row][0];
        float pk = red[0][row][1] + red[1][row][1] + red[2][row][1] + red[3][row][1];
        float pd = red[0][row][2] + red[1][row][2] + red[2][row][2] + red[3][row][2];
        size_t o = (((size_t)ct * B_ + b) * L_ + (r0 + row)) * 3;
        part[o + 0] = pq; part[o + 1] = pk; part[o + 2] = pd;
    }
}

// ---------------------------------------------------------------------------
// reduce partials -> p; flag borderline rows for fp32 fixup
// ---------------------------------------------------------------------------
__global__ __launch_bounds__(256) void cos_reduce(
    const float* __restrict__ part, float* __restrict__ p,
    int* __restrict__ fix_cnt, int* __restrict__ fix_list)
{
    int idx = blockIdx.x * 256 + threadIdx.x;
    if (idx >= B_ * L_) return;
    int b = idx / L_;
    int tpos = idx % L_;
    if (tpos == 0) { p[idx] = 1.0f; return; }
    int l = tpos - 1;
    float nq = 0.f, nk = 0.f, dt = 0.f;
#pragma unroll
    for (int ct = 0; ct < NCT; ++ct) {
        size_t o = (((size_t)ct * B_ + b) * L_ + l) * 3;
        nq += part[o + 0];
        nk += part[o + 1];
        dt += part[o + 2];
    }
    float qn = sqrtf(nq); if (qn < 1e-12f) qn = 1e-12f;
    float kn = sqrtf(nk); if (kn < 1e-12f) kn = 1e-12f;
    float cs = dt / (qn * kn);
    float pr = 0.5f * (1.0f - cs);
    pr = fminf(fmaxf(pr, 0.0f), 1.0f);
    p[idx] = pr;
    if (fabsf(cs) < FIX_TAU) {
        int slot = atomicAdd(fix_cnt, 1);
        if (slot < MAXFIX) fix_list[slot] = idx;
    }
}

// ---------------------------------------------------------------------------
// fp32 fixup of borderline rows (exact GEMV, matches fp32 reference decisions)
// ---------------------------------------------------------------------------
__global__ __launch_bounds__(256) void fixup(
    const float* __restrict__ h, const float* __restrict__ wq,
    const float* __restrict__ wk, const int* __restrict__ fix_cnt,
    const int* __restrict__ fix_list, float* __restrict__ p)
{
    __shared__ float hl[D_], hl1[D_];
    __shared__ float redv[3][4];
    int n = *fix_cnt; if (n > MAXFIX) n = MAXFIX;
    for (int e = blockIdx.x; e < n; e += gridDim.x) {
        int idx = fix_list[e];
        int b = idx / L_, tpos = idx % L_, l = tpos - 1;
        const float* hrow = h + ((size_t)b * L_ + l) * D_;
        __syncthreads();
        for (int i = threadIdx.x; i < D_; i += 256) { hl[i] = hrow[i]; hl1[i] = hrow[i + D_]; }
        __syncthreads();
        float nq = 0.f, nk = 0.f, dt = 0.f;
        for (int cb = 0; cb < 2; ++cb) {
            int c = threadIdx.x + cb * 256;
            const float* wqr = wq + (size_t)c * D_;
            const float* wkr = wk + (size_t)c * D_;
            float qv = 0.f, kv = 0.f;
            for (int k = 0; k < D_; ++k) { qv += hl[k] * wqr[k]; kv += hl1[k] * wkr[k]; }
            nq += qv * qv; nk += kv * kv; dt += qv * kv;
        }
        for (int off = 1; off < 64; off <<= 1) {
            nq += __shfl_xor(nq, off);
            nk += __shfl_xor(nk, off);
            dt += __shfl_xor(dt, off);
        }
        int wid = threadIdx.x >> 6, lane = threadIdx.x & 63;
        if (lane == 0) { redv[0][wid] = nq; redv[1][wid] = nk; redv[2][wid] = dt; }
        __syncthreads();
        if (threadIdx.x == 0) {
            nq = redv[0][0] + redv[0][1] + redv[0][2] + redv[0][3];
            nk = redv[1][0] + redv[1][1] + redv[1][2] + redv[1][3];
            dt = redv[2][0] + redv[2][1] + redv[2][2] + redv[2][3];
            float qn = sqrtf(nq); if (qn < 1e-12f) qn = 1e-12f;
            float kn = sqrtf(nk); if (kn < 1e-12f) kn = 1e-12f;
            float cs = dt / (qn * kn);
            float pr = 0.5f * (1.0f - cs);
            pr = fminf(fmaxf(pr, 0.0f), 1.0f);
            p[idx] = pr;
        }
    }
}

// ---------------------------------------------------------------------------
// EMA scan (unchanged from round 1 — verified correct)
// ---------------------------------------------------------------------------
__global__ __launch_bounds__(512) void scan_a(
    const float* __restrict__ h, const float* __restrict__ p,
    float* __restrict__ Bc, float* __restrict__ Ac)
{
    const int d = threadIdx.x;
    const int c = blockIdx.x;
    const int b = blockIdx.y;
    const int l0 = c * CHUNK;

    const float* hb = h + ((size_t)b * L_ + l0) * D_ + d;
    const float* pb = p + (size_t)b * L_ + l0;

    float st = 0.f;
    float ap = 1.f;
    for (int i = 0; i < CHUNK; ++i) {
        float pr = pb[i];
        if (pr > 0.5f) {
            float a = 1.f - pr;
            st = a * st + pr * hb[(size_t)i * D_];
            ap *= a;
        }
    }
    Bc[((size_t)b * NCHUNK + c) * D_ + d] = st;
    if (d == 0) Ac[b * NCHUNK + c] = ap;
}

__global__ __launch_bounds__(512) void scan_b(
    const float* __restrict__ Ac, const float* __restrict__ Bc,
    const float* __restrict__ det, float* __restrict__ carry)
{
    const int d = threadIdx.x;
    const int b = blockIdx.x;
    float st = det[(size_t)b * D_ + d];
    for (int c = 0; c < NCHUNK; ++c) {
        carry[((size_t)b * NCHUNK + c) * D_ + d] = st;
        st = Ac[b * NCHUNK + c] * st + Bc[((size_t)b * NCHUNK + c) * D_ + d];
    }
}

__global__ __launch_bounds__(512) void scan_c(
    const float* __restrict__ h, const float* __restrict__ p,
    const float* __restrict__ res, const float* __restrict__ carry,
    float* __restrict__ out)
{
    const int d = threadIdx.x;
    const int c = blockIdx.x;
    const int b = blockIdx.y;
    const int l0 = c * CHUNK;

    size_t base = ((size_t)b * L_ + l0) * D_ + d;
    const float* pb = p + (size_t)b * L_ + l0;

    float st = carry[((size_t)b * NCHUNK + c) * D_ + d];
    for (int i = 0; i < CHUNK; ++i) {
        float pr = pb[i];
        if (pr > 0.5f) {
            st = (1.f - pr) * st + pr * h[base + (size_t)i * D_];
        }
        out[base + (size_t)i * D_] = res[base + (size_t)i * D_] + st;
    }
}

// ---------------------------------------------------------------------------
extern "C" void kernel_launch(void* const* d_in, const int* in_sizes, int n_in,
                              void* d_out, int out_size, void* d_ws, size_t ws_size,
                              hipStream_t stream)
{
    const float* h   = (const float*)d_in[0];
    const float* res = (const float*)d_in[1];
    const float* wq  = (const float*)d_in[2];
    const float* wk  = (const float*)d_in[3];
    const float* det = (const float*)d_in[4];
    float* out = (float*)d_out;

    // ws layout
    float* ws = (float*)d_ws;
    float* part  = ws;                                     // NCT*B*L*3 = 393216 f
    float* p     = part + (size_t)NCT * B_ * L_ * 3;       // 32768 f
    float* Ac    = p + (size_t)B_ * L_;                    // 256 f
    float* Bc    = Ac + (size_t)B_ * NCHUNK;               // 131072 f
    float* carry = Bc + (size_t)B_ * NCHUNK * D_;          // 131072 f
    int*  fix_cnt  = (int*)(carry + (size_t)B_ * NCHUNK * D_); // 4 ints
    int*  fix_list = fix_cnt + 4;                          // 16380 ints
    u16* wqh = (u16*)(fix_list + MAXFIX);                  // D*D each
    u16* wql = wqh + (size_t)D_ * D_;
    u16* wkh = wql + (size_t)D_ * D_;
    u16* wkl = wkh + (size_t)D_ * D_;

    conv_w<<<(D_ * D_ + 255) / 256, 256, 0, stream>>>(wq, wk, wqh, wql, wkh, wkl);
    zero_fix<<<1, 64, 0, stream>>>(fix_cnt);
    qk_mfma<<<dim3(NCT, NRT, B_), 256, 0, stream>>>(h, wqh, wql, wkh, wkl, part);
    cos_reduce<<<(B_ * L_ + 255) / 256, 256, 0, stream>>>(part, p, fix_cnt, fix_list);
    fixup<<<120, 256, 0, stream>>>(h, wq, wk, fix_cnt, fix_list, p);
    scan_a<<<dim3(NCHUNK, B_), 512, 0, stream>>>(h, p, Bc, Ac);
    scan_b<<<B_, 512, 0, stream>>>(Ac, Bc, det, carry);
    scan_c<<<dim3(NCHUNK, B_), 512, 0, stream>>>(h, p, res, carry, out);
}